// Round 2
// baseline (173.581 us; speedup 1.0000x reference)
//
#include <hip/hip_runtime.h>
#include <hip/hip_cooperative_groups.h>
#include <math.h>

namespace cg = cooperative_groups;

// Problem constants (from reference setup_inputs)
#define N_NODES  2048
#define N_GRAPHS 128
#define NSUB     32
#define SSZ      10
#define NPAIRS   45
#define FEAT     96
#define HIDDEN   128
#define BN_EPS   1e-5f

#define NB       512   // blocks (4 waves each -> 2048 waves, 1 row per wave)
#define RPB      4     // rows per block

// ws float offsets
#define WS_C1 0
#define WS_C2 2048
#define WS_C3 4096

__global__ __launch_bounds__(256, 2)
void rwgnn_fused(const float* __restrict__ adj,
                 const int*   __restrict__ gi,
                 const float* __restrict__ theta,
                 const float* __restrict__ gamma,
                 const float* __restrict__ beta,
                 const float* __restrict__ w1,
                 const float* __restrict__ b1,
                 const float* __restrict__ w2,
                 const float* __restrict__ b2,
                 float* __restrict__ out,
                 float* __restrict__ ws)
{
    cg::grid_group grid = cg::this_grid();

    __shared__ __align__(16) float rows[RPB][N_NODES];   // 32 KB: this block's adjacency rows
    __shared__ float cnt[N_GRAPHS];
    __shared__ float C[3][N_GRAPHS];
    __shared__ float Vl[3][NSUB];
    __shared__ float yl[3][N_GRAPHS];
    __shared__ float mv[6];            // my[0..2], vy[0..2]
    __shared__ float xr[FEAT];
    __shared__ float red[4];

    const int tid  = threadIdx.x;
    const int wv   = tid >> 6;
    const int lane = tid & 63;
    const int row  = blockIdx.x * RPB + wv;

    float* c1 = ws + WS_C1;
    float* c2 = ws + WS_C2;
    float* c3 = ws + WS_C3;

    // ---- P1: stream adjacency row -> LDS; c1[row] = rowsum (= A@1) ----
    {
        const float* Ar = adj + (size_t)row * N_NODES;
        float s = 0.f;
        for (int c = lane * 4; c < N_NODES; c += 256) {
            float4 a = *reinterpret_cast<const float4*>(Ar + c);
            *reinterpret_cast<float4*>(&rows[wv][c]) = a;
            s += (a.x + a.y) + (a.z + a.w);
        }
        #pragma unroll
        for (int o = 32; o; o >>= 1) s += __shfl_down(s, o);
        if (lane == 0) c1[row] = s;
    }
    grid.sync();

    // ---- P2: c2[row] = row . c1  (= A^2 @ 1) ----
    {
        float s = 0.f;
        for (int c = lane * 4; c < N_NODES; c += 256) {
            float4 a = *reinterpret_cast<const float4*>(&rows[wv][c]);
            float4 x = *reinterpret_cast<const float4*>(c1 + c);
            s += a.x * x.x + a.y * x.y + a.z * x.z + a.w * x.w;
        }
        #pragma unroll
        for (int o = 32; o; o >>= 1) s += __shfl_down(s, o);
        if (lane == 0) c2[row] = s;
    }
    grid.sync();

    // ---- P3: c3[row] = row . c2  (= A^3 @ 1) ----
    {
        float s = 0.f;
        for (int c = lane * 4; c < N_NODES; c += 256) {
            float4 a = *reinterpret_cast<const float4*>(&rows[wv][c]);
            float4 x = *reinterpret_cast<const float4*>(c2 + c);
            s += a.x * x.x + a.y * x.y + a.z * x.z + a.w * x.w;
        }
        #pragma unroll
        for (int o = 32; o; o >>= 1) s += __shfl_down(s, o);
        if (lane == 0) c3[row] = s;
    }
    grid.sync();

    // ---- P4+P5: first 128 blocks each (redundantly) compute the fuse, then
    //      the MLP for their own graph g = blockIdx.x. Others are done. ----
    if (blockIdx.x >= N_GRAPHS) return;
    const int g = blockIdx.x;

    if (tid < N_GRAPHS) {
        cnt[tid] = 0.f; C[0][tid] = 0.f; C[1][tid] = 0.f; C[2][tid] = 0.f;
    }
    __syncthreads();

    // segment sums over nodes (LDS atomics; 8 nodes/thread)
    for (int n = tid; n < N_NODES; n += 256) {
        int gg = gi[n];
        atomicAdd(&cnt[gg], 1.f);
        atomicAdd(&C[0][gg], c1[n]);
        atomicAdd(&C[1][gg], c2[n]);
        atomicAdd(&C[2][gg], c3[n]);
    }

    // V_i[s] = 1^T A_s^i 1 without materializing A_s:
    //   u1 = A_s 1;  V1 = 2*sum(t);  V2 = ||u1||^2;  V3 = 2*sum_p t_p u1[i_p] u1[j_p]
    if (tid < NSUB) {
        const float* th = theta + tid * NPAIRS;
        float u1[SSZ];
        #pragma unroll
        for (int k = 0; k < SSZ; k++) u1[k] = 0.f;
        float sumT = 0.f;
        #pragma unroll
        for (int i = 0; i < SSZ; i++) {
            #pragma unroll
            for (int j = i + 1; j < SSZ; j++) {
                const int p = i * (2 * SSZ - 1 - i) / 2 + (j - i - 1);
                float t = th[p]; t = t > 0.f ? t : 0.f;
                sumT += t; u1[i] += t; u1[j] += t;
            }
        }
        float V2 = 0.f;
        #pragma unroll
        for (int k = 0; k < SSZ; k++) V2 += u1[k] * u1[k];
        float V3 = 0.f;
        #pragma unroll
        for (int i = 0; i < SSZ; i++) {
            #pragma unroll
            for (int j = i + 1; j < SSZ; j++) {
                const int p = i * (2 * SSZ - 1 - i) / 2 + (j - i - 1);
                float t = th[p]; t = t > 0.f ? t : 0.f;
                V3 += t * u1[i] * u1[j];
            }
        }
        Vl[0][tid] = 2.f * sumT;
        Vl[1][tid] = V2;
        Vl[2][tid] = 2.f * V3;
    }
    __syncthreads();   // covers the atomic loop and V writes

    // y_i[g'] = C_i[g'] / counts[g']
    if (tid < N_GRAPHS) {
        float inv = 1.f / cnt[tid];
        yl[0][tid] = C[0][tid] * inv;
        yl[1][tid] = C[1][tid] * inv;
        yl[2][tid] = C[2][tid] * inv;
    }
    __syncthreads();

    // per-step batch mean/var over 128 graphs: wave i handles step i
    if (wv < 3) {
        float a = yl[wv][lane], b = yl[wv][lane + 64];
        float s = a + b;
        #pragma unroll
        for (int o = 32; o; o >>= 1) s += __shfl_xor(s, o);
        float m = s * (1.f / N_GRAPHS);
        float da = a - m, db = b - m;
        float v = da * da + db * db;
        #pragma unroll
        for (int o = 32; o; o >>= 1) v += __shfl_xor(v, o);
        v *= (1.f / N_GRAPHS);
        if (lane == 0) { mv[wv] = m; mv[3 + wv] = v; }
    }
    __syncthreads();

    // normalized feature row for this block's graph:
    // x[g,f] = V_f * y_i[g]; mean_f = V_f*my_i; var_f = V_f^2*vy_i
    if (tid < FEAT) {
        int i = tid >> 5;
        float V = Vl[i][tid & 31];
        float scale = gamma[tid] * rsqrtf(V * V * mv[3 + i] + BN_EPS);
        xr[tid] = scale * V * (yl[i][g] - mv[i]) + beta[tid];
    }
    __syncthreads();

    // MLP: h = relu(x @ w1 + b1); out = h @ w2 + b2
    if (tid < HIDDEN) {
        float acc = b1[tid];
        #pragma unroll
        for (int f = 0; f < FEAT; f++)
            acc = fmaf(xr[f], w1[f * HIDDEN + tid], acc);
        float h = fmaxf(acc, 0.f);
        float2 w2v = *reinterpret_cast<const float2*>(w2 + 2 * tid);
        float p0 = h * w2v.x, p1 = h * w2v.y;
        #pragma unroll
        for (int o = 32; o; o >>= 1) { p0 += __shfl_down(p0, o); p1 += __shfl_down(p1, o); }
        int w = tid >> 6, l = tid & 63;
        if (l == 0) { red[2 * w] = p0; red[2 * w + 1] = p1; }
    }
    __syncthreads();
    if (tid == 0) {
        out[2 * g + 0] = red[0] + red[2] + b2[0];
        out[2 * g + 1] = red[1] + red[3] + b2[1];
    }
}

extern "C" void kernel_launch(void* const* d_in, const int* in_sizes, int n_in,
                              void* d_out, int out_size, void* d_ws, size_t ws_size,
                              hipStream_t stream) {
    const float* adj   = (const float*)d_in[0];
    const int*   gi    = (const int*)  d_in[1];
    const float* theta = (const float*)d_in[2];
    const float* gamma = (const float*)d_in[3];
    const float* beta  = (const float*)d_in[4];
    const float* w1    = (const float*)d_in[5];
    const float* b1    = (const float*)d_in[6];
    const float* w2    = (const float*)d_in[7];
    const float* b2    = (const float*)d_in[8];
    float* out = (float*)d_out;
    float* ws  = (float*)d_ws;

    void* args[] = { (void*)&adj, (void*)&gi, (void*)&theta, (void*)&gamma,
                     (void*)&beta, (void*)&w1, (void*)&b1, (void*)&w2,
                     (void*)&b2, (void*)&out, (void*)&ws };
    hipLaunchCooperativeKernel(reinterpret_cast<const void*>(rwgnn_fused),
                               dim3(NB), dim3(256), args, 0, stream);
}

// Round 3
// 166.908 us; speedup vs baseline: 1.0400x; 1.0400x over previous
//
#include <hip/hip_runtime.h>
#include <math.h>

// Problem constants (from reference setup_inputs)
#define N_NODES  2048
#define N_GRAPHS 128
#define NSUB     32
#define SSZ      10
#define NPAIRS   45
#define FEAT     96
#define HIDDEN   128
#define BN_EPS   1e-5f

#define NBLK     256   // one block per CU -> all co-resident, barrier is safe
#define RPB      8     // adjacency rows per block (8 x 8KB = 64KB LDS)

// ws float offsets
#define WS_C1   0
#define WS_C2   2048
#define WS_C3   4096
#define WS_BAR  6144   // 2 ints: cnt, gen  (memset to 0 each call)

// Device-scope barrier: one arrival per block, spin on generation counter.
// Correct under per-XCD non-coherent L2s: __threadfence() emits the
// agent-scope writeback/invalidate; atomics are device-scope.
__device__ inline void gbar(int* cnt, int* gen) {
    __threadfence();                       // release my global stores
    __syncthreads();
    if (threadIdx.x == 0) {
        int g0 = __hip_atomic_load(gen, __ATOMIC_RELAXED, __HIP_MEMORY_SCOPE_AGENT);
        int old = __hip_atomic_fetch_add(cnt, 1, __ATOMIC_ACQ_REL, __HIP_MEMORY_SCOPE_AGENT);
        if (old == NBLK - 1) {
            __hip_atomic_store(cnt, 0, __ATOMIC_RELAXED, __HIP_MEMORY_SCOPE_AGENT);
            __hip_atomic_fetch_add(gen, 1, __ATOMIC_RELEASE, __HIP_MEMORY_SCOPE_AGENT);
        } else {
            while (__hip_atomic_load(gen, __ATOMIC_ACQUIRE, __HIP_MEMORY_SCOPE_AGENT) == g0)
                __builtin_amdgcn_s_sleep(1);
        }
    }
    __syncthreads();
    __threadfence();                       // acquire: drop stale cache lines
}

__global__ __launch_bounds__(256, 1)
void rwgnn_persist(const float* __restrict__ adj,
                   const int*   __restrict__ gi,
                   const float* __restrict__ theta,
                   const float* __restrict__ gamma,
                   const float* __restrict__ beta,
                   const float* __restrict__ w1,
                   const float* __restrict__ b1,
                   const float* __restrict__ w2,
                   const float* __restrict__ b2,
                   float* __restrict__ out,
                   float* __restrict__ ws)
{
    __shared__ __align__(16) float rows[RPB][N_NODES];   // 64 KB
    __shared__ float cnt_s[N_GRAPHS];
    __shared__ float C[3][N_GRAPHS];
    __shared__ float Vl[3][NSUB];
    __shared__ float yl[3][N_GRAPHS];
    __shared__ float mv[6];
    __shared__ float xr[FEAT];
    __shared__ float red[4];

    const int tid  = threadIdx.x;
    const int wv   = tid >> 6;
    const int lane = tid & 63;

    float* c1 = ws + WS_C1;
    float* c2 = ws + WS_C2;
    float* c3 = ws + WS_C3;
    int*   bcnt = (int*)(ws + WS_BAR);
    int*   bgen = bcnt + 1;

    // ---- P1: stream my 2 rows/wave -> LDS; c1[row] = rowsum ----
    #pragma unroll
    for (int r = 0; r < 2; r++) {
        const int lw  = wv * 2 + r;
        const int row = blockIdx.x * RPB + lw;
        const float* Ar = adj + (size_t)row * N_NODES;
        float s = 0.f;
        for (int c = lane * 4; c < N_NODES; c += 256) {
            float4 a = *reinterpret_cast<const float4*>(Ar + c);
            *reinterpret_cast<float4*>(&rows[lw][c]) = a;
            s += (a.x + a.y) + (a.z + a.w);
        }
        #pragma unroll
        for (int o = 32; o; o >>= 1) s += __shfl_down(s, o);
        if (lane == 0) c1[row] = s;
    }
    gbar(bcnt, bgen);

    // ---- P2: c2[row] = rows[lw] . c1 ----
    #pragma unroll
    for (int r = 0; r < 2; r++) {
        const int lw  = wv * 2 + r;
        const int row = blockIdx.x * RPB + lw;
        float s = 0.f;
        for (int c = lane * 4; c < N_NODES; c += 256) {
            float4 a = *reinterpret_cast<const float4*>(&rows[lw][c]);
            float4 x = *reinterpret_cast<const float4*>(c1 + c);
            s += a.x * x.x + a.y * x.y + a.z * x.z + a.w * x.w;
        }
        #pragma unroll
        for (int o = 32; o; o >>= 1) s += __shfl_down(s, o);
        if (lane == 0) c2[row] = s;
    }
    gbar(bcnt, bgen);

    // ---- P3: c3[row] = rows[lw] . c2 ----
    #pragma unroll
    for (int r = 0; r < 2; r++) {
        const int lw  = wv * 2 + r;
        const int row = blockIdx.x * RPB + lw;
        float s = 0.f;
        for (int c = lane * 4; c < N_NODES; c += 256) {
            float4 a = *reinterpret_cast<const float4*>(&rows[lw][c]);
            float4 x = *reinterpret_cast<const float4*>(c2 + c);
            s += a.x * x.x + a.y * x.y + a.z * x.z + a.w * x.w;
        }
        #pragma unroll
        for (int o = 32; o; o >>= 1) s += __shfl_down(s, o);
        if (lane == 0) c3[row] = s;
    }
    gbar(bcnt, bgen);

    // ---- Tail: blocks 0..127 each (redundantly) compute BN pieces, then the
    //      MLP for their own graph. Blocks 128..255 are done. ----
    if (blockIdx.x >= N_GRAPHS) return;
    const int g = blockIdx.x;

    if (tid < N_GRAPHS) {
        cnt_s[tid] = 0.f; C[0][tid] = 0.f; C[1][tid] = 0.f; C[2][tid] = 0.f;
    }
    __syncthreads();

    for (int n = tid; n < N_NODES; n += 256) {
        int gg = gi[n];
        atomicAdd(&cnt_s[gg], 1.f);
        atomicAdd(&C[0][gg], c1[n]);
        atomicAdd(&C[1][gg], c2[n]);
        atomicAdd(&C[2][gg], c3[n]);
    }

    // V_i[s] = 1^T A_s^i 1 without materializing A_s
    if (tid < NSUB) {
        const float* th = theta + tid * NPAIRS;
        float u1[SSZ];
        #pragma unroll
        for (int k = 0; k < SSZ; k++) u1[k] = 0.f;
        float sumT = 0.f;
        #pragma unroll
        for (int i = 0; i < SSZ; i++) {
            #pragma unroll
            for (int j = i + 1; j < SSZ; j++) {
                const int p = i * (2 * SSZ - 1 - i) / 2 + (j - i - 1);
                float t = th[p]; t = t > 0.f ? t : 0.f;
                sumT += t; u1[i] += t; u1[j] += t;
            }
        }
        float V2 = 0.f;
        #pragma unroll
        for (int k = 0; k < SSZ; k++) V2 += u1[k] * u1[k];
        float V3 = 0.f;
        #pragma unroll
        for (int i = 0; i < SSZ; i++) {
            #pragma unroll
            for (int j = i + 1; j < SSZ; j++) {
                const int p = i * (2 * SSZ - 1 - i) / 2 + (j - i - 1);
                float t = th[p]; t = t > 0.f ? t : 0.f;
                V3 += t * u1[i] * u1[j];
            }
        }
        Vl[0][tid] = 2.f * sumT;
        Vl[1][tid] = V2;
        Vl[2][tid] = 2.f * V3;
    }
    __syncthreads();

    if (tid < N_GRAPHS) {
        float inv = 1.f / cnt_s[tid];
        yl[0][tid] = C[0][tid] * inv;
        yl[1][tid] = C[1][tid] * inv;
        yl[2][tid] = C[2][tid] * inv;
    }
    __syncthreads();

    // batch mean/var over 128 graphs: wave i handles step i
    if (wv < 3) {
        float a = yl[wv][lane], b = yl[wv][lane + 64];
        float s = a + b;
        #pragma unroll
        for (int o = 32; o; o >>= 1) s += __shfl_xor(s, o);
        float m = s * (1.f / N_GRAPHS);
        float da = a - m, db = b - m;
        float v = da * da + db * db;
        #pragma unroll
        for (int o = 32; o; o >>= 1) v += __shfl_xor(v, o);
        v *= (1.f / N_GRAPHS);
        if (lane == 0) { mv[wv] = m; mv[3 + wv] = v; }
    }
    __syncthreads();

    if (tid < FEAT) {
        int i = tid >> 5;
        float V = Vl[i][tid & 31];
        float scale = gamma[tid] * rsqrtf(V * V * mv[3 + i] + BN_EPS);
        xr[tid] = scale * V * (yl[i][g] - mv[i]) + beta[tid];
    }
    __syncthreads();

    if (tid < HIDDEN) {
        float acc = b1[tid];
        #pragma unroll
        for (int f = 0; f < FEAT; f++)
            acc = fmaf(xr[f], w1[f * HIDDEN + tid], acc);
        float h = fmaxf(acc, 0.f);
        float2 w2v = *reinterpret_cast<const float2*>(w2 + 2 * tid);
        float p0 = h * w2v.x, p1 = h * w2v.y;
        #pragma unroll
        for (int o = 32; o; o >>= 1) { p0 += __shfl_down(p0, o); p1 += __shfl_down(p1, o); }
        int w = tid >> 6, l = tid & 63;
        if (l == 0) { red[2 * w] = p0; red[2 * w + 1] = p1; }
    }
    __syncthreads();
    if (tid == 0) {
        out[2 * g + 0] = red[0] + red[2] + b2[0];
        out[2 * g + 1] = red[1] + red[3] + b2[1];
    }
}

extern "C" void kernel_launch(void* const* d_in, const int* in_sizes, int n_in,
                              void* d_out, int out_size, void* d_ws, size_t ws_size,
                              hipStream_t stream) {
    const float* adj   = (const float*)d_in[0];
    const int*   gi    = (const int*)  d_in[1];
    const float* theta = (const float*)d_in[2];
    const float* gamma = (const float*)d_in[3];
    const float* beta  = (const float*)d_in[4];
    const float* w1    = (const float*)d_in[5];
    const float* b1    = (const float*)d_in[6];
    const float* w2    = (const float*)d_in[7];
    const float* b2    = (const float*)d_in[8];
    float* out = (float*)d_out;
    float* ws  = (float*)d_ws;

    // zero the barrier counters (cnt, gen) every call — graph-legal async memset
    hipMemsetAsync((char*)d_ws + WS_BAR * sizeof(float), 0, 2 * sizeof(int), stream);

    rwgnn_persist<<<NBLK, 256, 0, stream>>>(adj, gi, theta, gamma, beta,
                                            w1, b1, w2, b2, out, ws);
}

// Round 4
// 38.944 us; speedup vs baseline: 4.4572x; 4.2858x over previous
//
#include <hip/hip_runtime.h>
#include <math.h>

// Problem constants (from reference setup_inputs)
#define N_NODES  2048
#define N_GRAPHS 128
#define NSUB     32
#define SSZ      10
#define NPAIRS   45
#define FEAT     96
#define HIDDEN   128
#define BN_EPS   1e-5f

#define NBLK     512    // 2 blocks/CU -> all co-resident (tiny LDS, low VGPR)
#define ROWS_PB  4      // adjacency rows per block, 1 per wave

// ws float offsets
#define WS_C1   0
#define WS_C2   2048
#define WS_C3   4096
#define WS_FLG  6144            // int flags[3][512]
#define WS_GEN  (6144 + 2048)   // int gen, in its own region

// Cache-bypassing relaxed atomics: complete at the device coherence point,
// so cross-XCD visibility needs NO wbl2/inv fences at all.
__device__ __forceinline__ float aload(const float* p) {
    return __hip_atomic_load(const_cast<float*>(p), __ATOMIC_RELAXED, __HIP_MEMORY_SCOPE_AGENT);
}
__device__ __forceinline__ void astore(float* p, float v) {
    __hip_atomic_store(p, v, __ATOMIC_RELAXED, __HIP_MEMORY_SCOPE_AGENT);
}
__device__ __forceinline__ int aiload(int* p) {
    return __hip_atomic_load(p, __ATOMIC_RELAXED, __HIP_MEMORY_SCOPE_AGENT);
}
__device__ __forceinline__ void aistore(int* p, int v) {
    __hip_atomic_store(p, v, __ATOMIC_RELAXED, __HIP_MEMORY_SCOPE_AGENT);
}

// Zero-fence, zero-RMW grid barrier.
// Release: __syncthreads() drains every wave's vmcnt (all bypassing data
// stores complete at the coherence point), then one relaxed flag store.
// Block 0 sweeps all flags in parallel (256 threads x 2), bumps gen.
// Others spin (relaxed, s_sleep backoff) on gen. Data reads afterwards are
// bypassing relaxed loads -> always fresh. No cache ops anywhere.
__device__ __forceinline__ void gbar(int* flags, int* gen, int phase) {
    __syncthreads();
    int* f = flags + (phase << 9);
    if (threadIdx.x == 0) aistore(f + blockIdx.x, 1);
    if (blockIdx.x == 0) {
        while (aiload(f + threadIdx.x) == 0) __builtin_amdgcn_s_sleep(1);
        while (aiload(f + threadIdx.x + 256) == 0) __builtin_amdgcn_s_sleep(1);
        __syncthreads();
        if (threadIdx.x == 0) aistore(gen, phase + 1);
    } else {
        if (threadIdx.x == 0) {
            while (aiload(gen) <= phase) __builtin_amdgcn_s_sleep(1);
        }
        __syncthreads();
    }
}

__global__ __launch_bounds__(256)
void rwgnn_persist(const float* __restrict__ adj,
                   const int*   __restrict__ gi,
                   const float* __restrict__ theta,
                   const float* __restrict__ gamma,
                   const float* __restrict__ beta,
                   const float* __restrict__ w1,
                   const float* __restrict__ b1,
                   const float* __restrict__ w2,
                   const float* __restrict__ b2,
                   float* __restrict__ out,
                   float* __restrict__ ws)
{
    __shared__ float cnt_s[N_GRAPHS];
    __shared__ float C[3][N_GRAPHS];
    __shared__ float Vl[3][NSUB];
    __shared__ float yl[3][N_GRAPHS];
    __shared__ float mv[6];
    __shared__ float xr[FEAT];
    __shared__ float red[4];

    const int tid  = threadIdx.x;
    const int wv   = tid >> 6;
    const int lane = tid & 63;
    const int bid  = blockIdx.x;

    float* c1 = ws + WS_C1;
    float* c2 = ws + WS_C2;
    float* c3 = ws + WS_C3;
    int* flags = (int*)(ws + WS_FLG);
    int* gen   = (int*)(ws + WS_GEN);

    const int row = bid * ROWS_PB + wv;
    const float* Ar = adj + (size_t)row * N_NODES;

    // ---- P1: c1[row] = rowsum(A) = (A @ 1)[row]; A read plain (cached, HBM/L3) ----
    {
        float s = 0.f;
        #pragma unroll
        for (int c = lane * 4; c < N_NODES; c += 256) {
            float4 a = *reinterpret_cast<const float4*>(Ar + c);
            s += (a.x + a.y) + (a.z + a.w);
        }
        #pragma unroll
        for (int o = 32; o; o >>= 1) s += __shfl_down(s, o);
        if (lane == 0) astore(&c1[row], s);
    }
    gbar(flags, gen, 0);

    // ---- P2: c2[row] = A[row] . c1 ; A plain cached, c1 bypassing ----
    {
        float s = 0.f;
        #pragma unroll
        for (int k = 0; k < 32; k++) {
            int idx = lane + (k << 6);
            s = fmaf(Ar[idx], aload(&c1[idx]), s);
        }
        #pragma unroll
        for (int o = 32; o; o >>= 1) s += __shfl_down(s, o);
        if (lane == 0) astore(&c2[row], s);
    }
    gbar(flags, gen, 1);

    // ---- P3: c3[row] = A[row] . c2 ----
    {
        float s = 0.f;
        #pragma unroll
        for (int k = 0; k < 32; k++) {
            int idx = lane + (k << 6);
            s = fmaf(Ar[idx], aload(&c2[idx]), s);
        }
        #pragma unroll
        for (int o = 32; o; o >>= 1) s += __shfl_down(s, o);
        if (lane == 0) astore(&c3[row], s);
    }
    gbar(flags, gen, 2);

    // ---- Tail: blocks 0..127 each (redundantly) compute stats, then the MLP
    //      for their own graph g = bid. Blocks 128..511 are done. ----
    if (bid >= N_GRAPHS) return;
    const int g = bid;

    if (tid < N_GRAPHS) {
        cnt_s[tid] = 0.f; C[0][tid] = 0.f; C[1][tid] = 0.f; C[2][tid] = 0.f;
    }
    __syncthreads();

    for (int n = tid; n < N_NODES; n += 256) {
        int gg = gi[n];
        atomicAdd(&cnt_s[gg], 1.f);
        atomicAdd(&C[0][gg], aload(&c1[n]));
        atomicAdd(&C[1][gg], aload(&c2[n]));
        atomicAdd(&C[2][gg], aload(&c3[n]));
    }

    // V_i[s] = 1^T A_s^i 1 without materializing A_s:
    //   u1 = A_s 1; V1 = 2*sum(t); V2 = ||u1||^2; V3 = 2*sum_p t_p u1[i_p] u1[j_p]
    if (tid < NSUB) {
        const float* th = theta + tid * NPAIRS;
        float u1[SSZ];
        #pragma unroll
        for (int k = 0; k < SSZ; k++) u1[k] = 0.f;
        float sumT = 0.f;
        #pragma unroll
        for (int i = 0; i < SSZ; i++) {
            #pragma unroll
            for (int j = i + 1; j < SSZ; j++) {
                const int p = i * (2 * SSZ - 1 - i) / 2 + (j - i - 1);
                float t = th[p]; t = t > 0.f ? t : 0.f;
                sumT += t; u1[i] += t; u1[j] += t;
            }
        }
        float V2 = 0.f;
        #pragma unroll
        for (int k = 0; k < SSZ; k++) V2 += u1[k] * u1[k];
        float V3 = 0.f;
        #pragma unroll
        for (int i = 0; i < SSZ; i++) {
            #pragma unroll
            for (int j = i + 1; j < SSZ; j++) {
                const int p = i * (2 * SSZ - 1 - i) / 2 + (j - i - 1);
                float t = th[p]; t = t > 0.f ? t : 0.f;
                V3 += t * u1[i] * u1[j];
            }
        }
        Vl[0][tid] = 2.f * sumT;
        Vl[1][tid] = V2;
        Vl[2][tid] = 2.f * V3;
    }
    __syncthreads();

    if (tid < N_GRAPHS) {
        float inv = 1.f / cnt_s[tid];
        yl[0][tid] = C[0][tid] * inv;
        yl[1][tid] = C[1][tid] * inv;
        yl[2][tid] = C[2][tid] * inv;
    }
    __syncthreads();

    // batch mean/var over 128 graphs: wave i handles step i
    if (wv < 3) {
        float a = yl[wv][lane], b = yl[wv][lane + 64];
        float s = a + b;
        #pragma unroll
        for (int o = 32; o; o >>= 1) s += __shfl_xor(s, o);
        float m = s * (1.f / N_GRAPHS);
        float da = a - m, db = b - m;
        float v = da * da + db * db;
        #pragma unroll
        for (int o = 32; o; o >>= 1) v += __shfl_xor(v, o);
        v *= (1.f / N_GRAPHS);
        if (lane == 0) { mv[wv] = m; mv[3 + wv] = v; }
    }
    __syncthreads();

    if (tid < FEAT) {
        int i = tid >> 5;
        float V = Vl[i][tid & 31];
        float scale = gamma[tid] * rsqrtf(V * V * mv[3 + i] + BN_EPS);
        xr[tid] = scale * V * (yl[i][g] - mv[i]) + beta[tid];
    }
    __syncthreads();

    if (tid < HIDDEN) {
        float acc = b1[tid];
        #pragma unroll
        for (int f = 0; f < FEAT; f++)
            acc = fmaf(xr[f], w1[f * HIDDEN + tid], acc);
        float h = fmaxf(acc, 0.f);
        float2 w2v = *reinterpret_cast<const float2*>(w2 + 2 * tid);
        float p0 = h * w2v.x, p1 = h * w2v.y;
        #pragma unroll
        for (int o = 32; o; o >>= 1) { p0 += __shfl_down(p0, o); p1 += __shfl_down(p1, o); }
        int w = tid >> 6, l = tid & 63;
        if (l == 0) { red[2 * w] = p0; red[2 * w + 1] = p1; }
    }
    __syncthreads();
    if (tid == 0) {
        out[2 * g + 0] = red[0] + red[2] + b2[0];
        out[2 * g + 1] = red[1] + red[3] + b2[1];
    }
}

extern "C" void kernel_launch(void* const* d_in, const int* in_sizes, int n_in,
                              void* d_out, int out_size, void* d_ws, size_t ws_size,
                              hipStream_t stream) {
    const float* adj   = (const float*)d_in[0];
    const int*   gi    = (const int*)  d_in[1];
    const float* theta = (const float*)d_in[2];
    const float* gamma = (const float*)d_in[3];
    const float* beta  = (const float*)d_in[4];
    const float* w1    = (const float*)d_in[5];
    const float* b1    = (const float*)d_in[6];
    const float* w2    = (const float*)d_in[7];
    const float* b2    = (const float*)d_in[8];
    float* out = (float*)d_out;
    float* ws  = (float*)d_ws;

    // zero flags[3][512] + gen each call (graph-legal async memset)
    hipMemsetAsync((char*)d_ws + WS_FLG * sizeof(float), 0,
                   (2048 + 1) * sizeof(int), stream);

    rwgnn_persist<<<NBLK, 256, 0, stream>>>(adj, gi, theta, gamma, beta,
                                            w1, b1, w2, b2, out, ws);
}